// Round 5
// baseline (207.709 us; speedup 1.0000x reference)
//
#include <hip/hip_runtime.h>
#include <hip/hip_bf16.h>

// ---------------------------------------------------------------------------
// Fusion_12867722019048 on MFMA. B=65536, IN=64, H=16.
//
// Factorization (verified): fusion[f = a*32 + mm*8 + l] = X[a]*Y2[mm]*Z[l],
// X/Z pairwise maxes, Y2 quad maxes of sigmoid projections (all >0).
//
// MFMA 16x16x32 bf16 layouts (HW-verified m89/m92):
//   A[m=lane&15][k=quad*8+j], B[n=lane&15][k=quad*8+j], D[m=quad*4+reg][n=lane&15].
// Fusion A-frag: k = t*32+quad*8+j = f with a=t, mm=quad, l=j ->
//   frag[j] = X[m][t]*Y2[m][quad]*Z[m][j]  (9 mults, no 256-wide tensor).
//
// Round-5 restructure (round 4 was latency-bound: VALUBusy 16%, MfmaUtil 4%,
// HBM 26%, occupancy capped at 4 waves/SIMD by the 16-samples/wave tiling):
//   - ALL input loads issued up front (28 x 16B/lane outstanding -> one
//     HBM-latency exposure instead of six).
//   - Separate LDS pool buffers per path -> path1/path2 proj+pool+fusion are
//     independent streams (8 parallel MFMA chains), no false LDS deps.
//   - mean gated+packed immediately after load.
// Zero __syncthreads: all LDS wave-private; in-wave DS ops are ordered.
// Weights pre-packed to bf16 frag tables in d_ws (92 KB, L2-hot).
// ---------------------------------------------------------------------------

typedef __attribute__((ext_vector_type(8))) short short8;
typedef __attribute__((ext_vector_type(4))) float f32x4;

#define MFMA16(A, B, C) __builtin_amdgcn_mfma_f32_16x16x32_bf16((A), (B), (C), 0, 0, 0)

__device__ __forceinline__ float fast_sigmoid(float x) {
    return __builtin_amdgcn_rcpf(1.0f + __expf(-x));
}
__device__ __forceinline__ float gate(float x, float rm) {
    return x * fast_sigmoid(fabsf(x - rm));   // eval-mode normGate2
}
__device__ __forceinline__ float lrelu(float x) {
    return x >= 0.0f ? x : 0.01f * x;
}
__device__ __forceinline__ short f2bf(float f) {
    union { float f; unsigned u; } x; x.f = f;
    unsigned r = (x.u + 0x7FFF + ((x.u >> 16) & 1)) >> 16;  // RNE
    return (short)r;
}
__device__ __forceinline__ short8 pack8(const float* xs) {
    union { short8 s; __hip_bfloat162 h[4]; } u;
    #pragma unroll
    for (int i = 0; i < 4; ++i) {
        float2 t; t.x = xs[2 * i]; t.y = xs[2 * i + 1];
        u.h[i] = __float22bfloat162_rn(t);
    }
    return u.s;
}
// Load this lane's two A-frags (k = t*32 + quad*8 + j) and pack to bf16.
__device__ __forceinline__ void load_pack(const float* __restrict__ p, short8 fr[2]) {
    const float4* q = (const float4*)p;
    float4 u0 = q[0], u1 = q[1], u2 = q[8], u3 = q[9];
    float x0[8] = {u0.x, u0.y, u0.z, u0.w, u1.x, u1.y, u1.z, u1.w};
    float x1[8] = {u2.x, u2.y, u2.z, u2.w, u3.x, u3.y, u3.z, u3.w};
    fr[0] = pack8(x0);
    fr[1] = pack8(x1);
}
__device__ __forceinline__ f32x4 pmax_xor(f32x4 v, int mask) {
    f32x4 r;
    #pragma unroll
    for (int i = 0; i < 4; ++i) r[i] = fmaxf(v[i], __shfl_xor(v[i], mask, 64));
    return r;
}

// sigmoid(x @ W^T + b) from pre-packed A-frags: H[sample=quad*4+reg][unit=lane&15]
__device__ __forceinline__ f32x4 proj_mfma(const short8 fr[2],
                                           const short8* __restrict__ wfr,
                                           const float* __restrict__ bias,
                                           int lane) {
    f32x4 acc; acc[0] = acc[1] = acc[2] = acc[3] = 0.0f;
    acc = MFMA16(fr[0], wfr[lane], acc);
    acc = MFMA16(fr[1], wfr[64 + lane], acc);
    const float bn = bias[lane & 15];
    f32x4 h;
    #pragma unroll
    for (int r = 0; r < 4; ++r) h[r] = fast_sigmoid(acc[r] + bn);
    return h;
}

// Pool + transpose into wave-private LDS: X8T[8][16], Y2T[4][16], Z8T[8][16].
// Duplicate-lane writes hit the same address with the same value (benign).
__device__ __forceinline__ void stage_pools(f32x4 hx, f32x4 hy, f32x4 hz, int lane,
                                            float* __restrict__ sX,
                                            float* __restrict__ sY,
                                            float* __restrict__ sZ) {
    const int quad = lane >> 4, ln = lane & 15;
    f32x4 X = pmax_xor(hx, 1);
    f32x4 Y = pmax_xor(pmax_xor(hy, 1), 2);
    f32x4 Z = pmax_xor(hz, 1);
    #pragma unroll
    for (int r = 0; r < 4; ++r) {
        const int sm = quad * 4 + r;
        sX[(ln >> 1) * 16 + sm] = X[r];
        sY[(ln >> 2) * 16 + sm] = Y[r];
        sZ[(ln >> 1) * 16 + sm] = Z[r];
    }
}

// acc[nt] = D tile [16 samples][16 cols], cols nt*16+(lane&15); K=256, 8 steps.
__device__ __forceinline__ void fusion_mfma(const short8* __restrict__ wfr,
                                            const float* __restrict__ bias,
                                            const float* __restrict__ sX,
                                            const float* __restrict__ sY,
                                            const float* __restrict__ sZ,
                                            int lane, f32x4 acc[4]) {
    const int m = lane & 15, quad = lane >> 4;
    #pragma unroll
    for (int nt = 0; nt < 4; ++nt) {
        const float bb = bias[nt * 16 + m];
        acc[nt][0] = acc[nt][1] = acc[nt][2] = acc[nt][3] = bb;
    }
    float zr[8];
    #pragma unroll
    for (int j = 0; j < 8; ++j) zr[j] = sZ[j * 16 + m];
    const float yq = sY[quad * 16 + m];
    #pragma unroll
    for (int t = 0; t < 8; ++t) {
        const float xy = sX[t * 16 + m] * yq;
        float p[8];
        #pragma unroll
        for (int j = 0; j < 8; ++j) p[j] = xy * zr[j];
        const short8 af = pack8(p);
        #pragma unroll
        for (int nt = 0; nt < 4; ++nt)
            acc[nt] = MFMA16(af, wfr[(t * 4 + nt) * 64 + lane], acc[nt]);
    }
}

__global__ __launch_bounds__(256, 4)
void fused_fwd(const float* __restrict__ a,  const float* __restrict__ v,
               const float* __restrict__ l,  const float* __restrict__ pa,
               const float* __restrict__ pv, const float* __restrict__ pl,
               const float* __restrict__ mean,
               const float* __restrict__ ba,  const float* __restrict__ bv_,
               const float* __restrict__ bl_, const float* __restrict__ bap,
               const float* __restrict__ bvp, const float* __restrict__ blp,
               const float* __restrict__ bf1, const float* __restrict__ bfp1,
               const float* __restrict__ bng,
               const float* __restrict__ rm1, const float* __restrict__ rm2,
               const short* __restrict__ ws, float* __restrict__ out) {
    __shared__ __align__(16) float sPoolA[4 * 320];  // path1: X8T|Y2T|Z8T per wave
    __shared__ __align__(16) float sPoolB[4 * 320];  // path2
    __shared__ __align__(16) short sF2[4 * 1280];    // gated F2 tile [16][80] bf16

    const int tid = threadIdx.x;
    const int lane = tid & 63;
    const int w = tid >> 6;
    const int m = lane & 15;
    const int quad = lane >> 4;
    const int srow0 = blockIdx.x * 64 + w * 16;

    float* sXA = sPoolA + w * 320; float* sYA = sXA + 128; float* sZA = sYA + 64;
    float* sXB = sPoolB + w * 320; float* sYB = sXB + 128; float* sZB = sYB + 64;
    short* sF = sF2 + w * 1280;

    const short8* projFr = (const short8*)ws;             // 6 x 128 frags
    const short8* wfFr   = (const short8*)(ws + 6144);    // Wf1:  32 x 64
    const short8* wfpFr  = (const short8*)(ws + 22528);   // Wfp1: 32 x 64
    const short8* wngFr  = (const short8*)(ws + 38912);   // Wng:  16 x 64

    const size_t off = (size_t)(srow0 + m) * 64 + quad * 8;

    // ---- issue ALL input loads up front (compiler keeps them in flight) ----
    short8 fPA[2], fPV[2], fPL[2], fA[2], fV[2], fL[2], fM[2];
    load_pack(pa + off, fPA);
    load_pack(pv + off, fPV);
    load_pack(pl + off, fPL);
    load_pack(a + off, fA);
    load_pack(v + off, fV);
    load_pack(l + off, fL);
    {   // mean: load, gate with rm1[64..128), pack (frees raw regs early)
        const float4* q = (const float4*)(mean + off);
        float4 u0 = q[0], u1 = q[1], u2 = q[8], u3 = q[9];
        const float4* r0p = (const float4*)(rm1 + 64 + quad * 8);
        const float4* r1p = (const float4*)(rm1 + 96 + quad * 8);
        float4 r0 = r0p[0], r1 = r0p[1], r2 = r1p[0], r3 = r1p[1];
        float g0[8] = { gate(u0.x, r0.x), gate(u0.y, r0.y), gate(u0.z, r0.z), gate(u0.w, r0.w),
                        gate(u1.x, r1.x), gate(u1.y, r1.y), gate(u1.z, r1.z), gate(u1.w, r1.w) };
        float g1[8] = { gate(u2.x, r2.x), gate(u2.y, r2.y), gate(u2.z, r2.z), gate(u2.w, r2.w),
                        gate(u3.x, r3.x), gate(u3.y, r3.y), gate(u3.z, r3.z), gate(u3.w, r3.w) };
        fM[0] = pack8(g0);
        fM[1] = pack8(g1);
    }

    // ---- projections: 6 independent MFMA pairs, then pools (separate LDS) --
    f32x4 hx2 = proj_mfma(fPA, projFr + 3 * 128, bap, lane);
    f32x4 hy2 = proj_mfma(fPV, projFr + 4 * 128, bvp, lane);
    f32x4 hz2 = proj_mfma(fPL, projFr + 5 * 128, blp, lane);
    f32x4 hx1 = proj_mfma(fA, projFr + 0 * 128, ba, lane);
    f32x4 hy1 = proj_mfma(fV, projFr + 1 * 128, bv_, lane);
    f32x4 hz1 = proj_mfma(fL, projFr + 2 * 128, bl_, lane);
    stage_pools(hx2, hy2, hz2, lane, sXB, sYB, sZB);
    stage_pools(hx1, hy1, hz1, lane, sXA, sYA, sZA);

    // ---- two independent fusion gemms (8 parallel MFMA chains) -------------
    f32x4 f2[4], f1[4];
    fusion_mfma(wfpFr, bfp1, sXB, sYB, sZB, lane, f2);
    fusion_mfma(wfFr,  bf1,  sXA, sYA, sZA, lane, f1);

    // gate(lrelu(fusion_2), rm1[0:64]) -> wave-private bf16 tile [16][80]
    #pragma unroll
    for (int nt = 0; nt < 4; ++nt) {
        const float r1 = rm1[nt * 16 + m];
        #pragma unroll
        for (int r = 0; r < 4; ++r) {
            const float g = gate(lrelu(f2[nt][r]), r1);
            sF[(quad * 4 + r) * 80 + nt * 16 + m] = f2bf(g);
        }
    }

    // ---- ng gemm: h = concat(F2g, gated mean) @ Wng^T + bng ----------------
    f32x4 h[4];
    #pragma unroll
    for (int nt = 0; nt < 4; ++nt) {
        const float bb = bng[nt * 16 + m];
        h[nt][0] = h[nt][1] = h[nt][2] = h[nt][3] = bb;
    }
    #pragma unroll
    for (int t = 0; t < 2; ++t) {   // k = 64..127: gated mean (pre-packed)
        #pragma unroll
        for (int nt = 0; nt < 4; ++nt)
            h[nt] = MFMA16(fM[t], wngFr[((2 + t) * 4 + nt) * 64 + lane], h[nt]);
    }
    #pragma unroll
    for (int t = 0; t < 2; ++t) {   // k = 0..63: F2g tile from LDS
        const short8 af = *(const short8*)(sF + m * 80 + t * 32 + quad * 8);
        #pragma unroll
        for (int nt = 0; nt < 4; ++nt)
            h[nt] = MFMA16(af, wngFr[(t * 4 + nt) * 64 + lane], h[nt]);
    }

    // ---- epilogue: gate with rm2, store ------------------------------------
    #pragma unroll
    for (int nt = 0; nt < 4; ++nt) {
        const float r2a = rm2[nt * 16 + m];
        const float r2b = rm2[64 + nt * 16 + m];
        #pragma unroll
        for (int r = 0; r < 4; ++r) {
            const size_t row = (size_t)(srow0 + quad * 4 + r) * 128;
            out[row + nt * 16 + m]      = gate(h[nt][r], r2a);
            out[row + 64 + nt * 16 + m] = gate(lrelu(f1[nt][r]), r2b);
        }
    }
}

// Pack all weights into bf16 frag-ordered tables:
//   frag element (t, nt, lane, j): row = nt*16+(lane&15), col = t*32+(lane>>4)*8+j.
// Layout (shorts): [0,6144) six 16x64 projs (Wa,Wv,Wl,Wap,Wvp,Wlp);
// [6144,22528) Wf1; [22528,38912) Wfp1; [38912,47104) Wng.
__global__ void build_frags(const float* __restrict__ Wa,  const float* __restrict__ Wv,
                            const float* __restrict__ Wl,  const float* __restrict__ Wap,
                            const float* __restrict__ Wvp, const float* __restrict__ Wlp,
                            const float* __restrict__ Wf1, const float* __restrict__ Wfp1,
                            const float* __restrict__ Wng, short* __restrict__ ws) {
    const int i = blockIdx.x * 256 + threadIdx.x;
    if (i >= 47104) return;
    float val;
    if (i < 6144) {
        const float* W[6] = {Wa, Wv, Wl, Wap, Wvp, Wlp};
        const int mi = i >> 10, r = i & 1023;
        const int t = r >> 9, lane = (r >> 3) & 63, j = r & 7;
        val = W[mi][(lane & 15) * 64 + t * 32 + (lane >> 4) * 8 + j];
    } else if (i < 38912) {
        int r = i - 6144;
        const float* W = (r < 16384) ? Wf1 : Wfp1;
        r &= 16383;
        const int tn = r >> 9, lane = (r >> 3) & 63, j = r & 7;
        const int t = tn >> 2, nt = tn & 3;
        val = W[(nt * 16 + (lane & 15)) * 256 + t * 32 + (lane >> 4) * 8 + j];
    } else {
        const int r = i - 38912;
        const int tn = r >> 9, lane = (r >> 3) & 63, j = r & 7;
        const int t = tn >> 2, nt = tn & 3;
        val = Wng[(nt * 16 + (lane & 15)) * 128 + t * 32 + (lane >> 4) * 8 + j];
    }
    ws[i] = f2bf(val);
}

extern "C" void kernel_launch(void* const* d_in, const int* in_sizes, int n_in,
                              void* d_out, int out_size, void* d_ws, size_t ws_size,
                              hipStream_t stream) {
    const float* a    = (const float*)d_in[0];
    const float* v    = (const float*)d_in[1];
    const float* l    = (const float*)d_in[2];
    const float* pa   = (const float*)d_in[3];
    const float* pv   = (const float*)d_in[4];
    const float* pl   = (const float*)d_in[5];
    const float* mean = (const float*)d_in[6];
    const float* Wa   = (const float*)d_in[7];
    const float* ba   = (const float*)d_in[8];
    const float* Wv   = (const float*)d_in[9];
    const float* bv   = (const float*)d_in[10];
    const float* Wl   = (const float*)d_in[11];
    const float* bl   = (const float*)d_in[12];
    const float* Wap  = (const float*)d_in[13];
    const float* bap  = (const float*)d_in[14];
    const float* Wvp  = (const float*)d_in[15];
    const float* bvp  = (const float*)d_in[16];
    const float* Wlp  = (const float*)d_in[17];
    const float* blp  = (const float*)d_in[18];
    const float* Wf1  = (const float*)d_in[19];
    const float* bf1  = (const float*)d_in[20];
    const float* Wfp1 = (const float*)d_in[21];
    const float* bfp1 = (const float*)d_in[22];
    const float* Wng  = (const float*)d_in[23];
    const float* bng  = (const float*)d_in[24];
    const float* rm1  = (const float*)d_in[25];
    const float* rm2  = (const float*)d_in[26];

    short* ws = (short*)d_ws;  // 47104 shorts = 92 KiB

    build_frags<<<184, 256, 0, stream>>>(Wa, Wv, Wl, Wap, Wvp, Wlp,
                                         Wf1, Wfp1, Wng, ws);
    fused_fwd<<<1024, 256, 0, stream>>>(a, v, l, pa, pv, pl, mean,
                                        ba, bv, bl, bap, bvp, blp,
                                        bf1, bfp1, bng, rm1, rm2,
                                        ws, (float*)d_out);
}